// Round 1
// baseline (4775.514 us; speedup 1.0000x reference)
//
#include <hip/hip_runtime.h>

#define NN 50000
#define NE 800000
#define DD 128
#define D4 32  // float4s per row

// ---------------- elementwise helpers ----------------

__global__ void copy_f4(const float4* __restrict__ in, float4* __restrict__ out, int n4) {
    int i = blockIdx.x * blockDim.x + threadIdx.x;
    if (i < n4) out[i] = in[i];
}

__global__ void zero_f4(float4* __restrict__ p, int n4) {
    int i = blockIdx.x * blockDim.x + threadIdx.x;
    if (i < n4) p[i] = make_float4(0.f, 0.f, 0.f, 0.f);
}

// ---------------- scatter-add: agg[dst] += x[src] * ew ----------------
// one thread per (edge, float4-chunk): 800000 * 32 threads

__global__ void scatter_kernel(const float* __restrict__ x, const int* __restrict__ ei,
                               const float* __restrict__ ew, float* __restrict__ agg) {
    int gid = blockIdx.x * blockDim.x + threadIdx.x;
    int e = gid >> 5;
    if (e >= NE) return;
    int c = (gid & 31) << 2;
    int src = ei[e];
    int dst = ei[NE + e];
    float w = ew[e];
    float4 v = *(const float4*)(x + (long long)src * DD + c);
    float* a = agg + (long long)dst * DD + c;
    atomicAdd(a + 0, v.x * w);
    atomicAdd(a + 1, v.y * w);
    atomicAdd(a + 2, v.z * w);
    atomicAdd(a + 3, v.w * w);
}

// ---------------- GEMM: out = act(A' @ W + b) ----------------
// MODE 0: A' = (1+eps)*A + A2, out = relu(..)          (gemm1)
// MODE 1: A' = A, out plain, accumulate col sum/sumsq  (gemm2 + BN stats)
// Block: 32 rows x 128 cols, 256 threads; thread = 4 rows x 4 cols.

template <int MODE>
__global__ void __launch_bounds__(256, 2) gemm_kernel(
    const float* __restrict__ A, const float* __restrict__ A2,
    const float* __restrict__ W, const float* __restrict__ bias,
    const float* __restrict__ epsp, float* __restrict__ out,
    float* __restrict__ stats) {
    __shared__ float4 Ws[4096];  // 128x128 weights, 64 KB
    __shared__ float4 As[1024];  // 32x128 A tile, 16 KB (reused for stat reduce)

    int tid = threadIdx.x;
    int tx = tid & 31;   // col group: cols 4*tx .. 4*tx+3
    int ty = tid >> 5;   // row group: rows ty*4 .. ty*4+3 (within tile)
    int r0 = blockIdx.x * 32;

    // stage W (coalesced)
    const float4* Wg = (const float4*)W;
#pragma unroll
    for (int i = 0; i < 16; i++) Ws[i * 256 + tid] = Wg[i * 256 + tid];

    // stage A tile (with fused GIN input for MODE 0)
    float epsv = (MODE == 0) ? (1.0f + *epsp) : 1.0f;
#pragma unroll
    for (int i = 0; i < 4; i++) {
        int idx = i * 256 + tid;
        int row = idx >> 5;
        int c4 = idx & 31;
        int gr = r0 + row;
        float4 v = make_float4(0.f, 0.f, 0.f, 0.f);
        if (gr < NN) {
            float4 a = ((const float4*)A)[gr * D4 + c4];
            if (MODE == 0) {
                float4 g = ((const float4*)A2)[gr * D4 + c4];
                v = make_float4(a.x * epsv + g.x, a.y * epsv + g.y,
                                a.z * epsv + g.z, a.w * epsv + g.w);
            } else {
                v = a;
            }
        }
        As[idx] = v;
    }
    __syncthreads();

    float4 acc[4];
#pragma unroll
    for (int r = 0; r < 4; r++) acc[r] = make_float4(0.f, 0.f, 0.f, 0.f);

#pragma unroll 8
    for (int kk = 0; kk < 32; kk++) {
        float4 a[4];
#pragma unroll
        for (int r = 0; r < 4; r++) a[r] = As[(ty * 4 + r) * 32 + kk];
        float4 w0 = Ws[(4 * kk + 0) * 32 + tx];
        float4 w1 = Ws[(4 * kk + 1) * 32 + tx];
        float4 w2 = Ws[(4 * kk + 2) * 32 + tx];
        float4 w3 = Ws[(4 * kk + 3) * 32 + tx];
#pragma unroll
        for (int r = 0; r < 4; r++) {
            acc[r].x += a[r].x * w0.x + a[r].y * w1.x + a[r].z * w2.x + a[r].w * w3.x;
            acc[r].y += a[r].x * w0.y + a[r].y * w1.y + a[r].z * w2.y + a[r].w * w3.y;
            acc[r].z += a[r].x * w0.z + a[r].y * w1.z + a[r].z * w2.z + a[r].w * w3.z;
            acc[r].w += a[r].x * w0.w + a[r].y * w1.w + a[r].z * w2.w + a[r].w * w3.w;
        }
    }

    float4 bv = ((const float4*)bias)[tx];
    float4* out4 = (float4*)out;

    if (MODE == 0) {
#pragma unroll
        for (int r = 0; r < 4; r++) {
            int gr = r0 + ty * 4 + r;
            if (gr < NN) {
                float4 v = make_float4(fmaxf(acc[r].x + bv.x, 0.f), fmaxf(acc[r].y + bv.y, 0.f),
                                       fmaxf(acc[r].z + bv.z, 0.f), fmaxf(acc[r].w + bv.w, 0.f));
                out4[gr * D4 + tx] = v;
            }
        }
    } else {
        float4 s = make_float4(0.f, 0.f, 0.f, 0.f);
        float4 s2 = make_float4(0.f, 0.f, 0.f, 0.f);
#pragma unroll
        for (int r = 0; r < 4; r++) {
            int gr = r0 + ty * 4 + r;
            if (gr < NN) {
                float4 v = make_float4(acc[r].x + bv.x, acc[r].y + bv.y,
                                       acc[r].z + bv.z, acc[r].w + bv.w);
                out4[gr * D4 + tx] = v;
                s.x += v.x; s.y += v.y; s.z += v.z; s.w += v.w;
                s2.x += v.x * v.x; s2.y += v.y * v.y; s2.z += v.z * v.z; s2.w += v.w * v.w;
            }
        }
        // cross-ty reduce via As (done reading it), then atomics into stats
        __syncthreads();
        As[ty * 32 + tx] = s;
        __syncthreads();
        if (ty == 0) {
            float4 t = As[tx];
#pragma unroll
            for (int j = 1; j < 8; j++) {
                float4 u = As[j * 32 + tx];
                t.x += u.x; t.y += u.y; t.z += u.z; t.w += u.w;
            }
            atomicAdd(&stats[tx * 4 + 0], t.x);
            atomicAdd(&stats[tx * 4 + 1], t.y);
            atomicAdd(&stats[tx * 4 + 2], t.z);
            atomicAdd(&stats[tx * 4 + 3], t.w);
        }
        __syncthreads();
        As[ty * 32 + tx] = s2;
        __syncthreads();
        if (ty == 0) {
            float4 t = As[tx];
#pragma unroll
            for (int j = 1; j < 8; j++) {
                float4 u = As[j * 32 + tx];
                t.x += u.x; t.y += u.y; t.z += u.z; t.w += u.w;
            }
            atomicAdd(&stats[DD + tx * 4 + 0], t.x);
            atomicAdd(&stats[DD + tx * 4 + 1], t.y);
            atomicAdd(&stats[DD + tx * 4 + 2], t.z);
            atomicAdd(&stats[DD + tx * 4 + 3], t.w);
        }
    }
}

// ---------------- BN apply + ReLU + residual: x += relu(bn(h)) ----------------

__global__ void bn_apply(const float* __restrict__ h, const float* __restrict__ stats,
                         const float* __restrict__ gamma, const float* __restrict__ beta,
                         float* __restrict__ x) {
    int i = blockIdx.x * blockDim.x + threadIdx.x;
    if (i >= NN * D4) return;
    int c4 = i & 31;
    const float invN = 1.0f / NN;
    float4 s = ((const float4*)stats)[c4];
    float4 s2 = ((const float4*)stats)[D4 + c4];
    float4 mu = make_float4(s.x * invN, s.y * invN, s.z * invN, s.w * invN);
    float4 var = make_float4(s2.x * invN - mu.x * mu.x, s2.y * invN - mu.y * mu.y,
                             s2.z * invN - mu.z * mu.z, s2.w * invN - mu.w * mu.w);
    float4 inv = make_float4(rsqrtf(var.x + 1e-5f), rsqrtf(var.y + 1e-5f),
                             rsqrtf(var.z + 1e-5f), rsqrtf(var.w + 1e-5f));
    float4 g = ((const float4*)gamma)[c4];
    float4 b = ((const float4*)beta)[c4];
    float4 hv = ((const float4*)h)[i];
    float4 xv = ((const float4*)x)[i];
    float4 v = make_float4(fmaxf(g.x * (hv.x - mu.x) * inv.x + b.x, 0.f),
                           fmaxf(g.y * (hv.y - mu.y) * inv.y + b.y, 0.f),
                           fmaxf(g.z * (hv.z - mu.z) * inv.z + b.z, 0.f),
                           fmaxf(g.w * (hv.w - mu.w) * inv.w + b.w, 0.f));
    ((float4*)x)[i] = make_float4(xv.x + v.x, xv.y + v.y, xv.z + v.z, xv.w + v.w);
}

// ---------------- launcher ----------------

extern "C" void kernel_launch(void* const* d_in, const int* in_sizes, int n_in,
                              void* d_out, int out_size, void* d_ws, size_t ws_size,
                              hipStream_t stream) {
    const float* x_in = (const float*)d_in[0];
    const int* ei = (const int*)d_in[1];
    // d_in[2] = edge_attr (unused)
    const float* ew = (const float*)d_in[3];
    const float* W1 = (const float*)d_in[4];
    const float* b1 = (const float*)d_in[5];
    const float* W2 = (const float*)d_in[6];
    const float* b2 = (const float*)d_in[7];
    const float* eps = (const float*)d_in[8];
    const float* gamma = (const float*)d_in[9];
    const float* beta = (const float*)d_in[10];

    float* x = (float*)d_out;  // running node features

    char* ws = (char*)d_ws;
    float* buf0 = (float*)ws;                           // agg, then h   (25.6 MB)
    float* stats = (float*)(ws + 25600000);             // 256 floats (sum | sumsq)
    float* buf1 = (float*)(ws + 25601024);              // t             (25.6 MB)

    const int n4x = NN * D4;                 // 1.6M float4 per node matrix
    const int nZero = (25600000 + 1024) / 16;  // buf0 + stats, float4 count

    // x = x_in
    copy_f4<<<(n4x + 255) / 256, 256, 0, stream>>>((const float4*)x_in, (float4*)x, n4x);

    for (int i = 0; i < 3; i++) {
        const float* W1i = W1 + i * DD * DD;
        const float* b1i = b1 + i * DD;
        const float* W2i = W2 + i * DD * DD;
        const float* b2i = b2 + i * DD;

        zero_f4<<<(nZero + 255) / 256, 256, 0, stream>>>((float4*)buf0, nZero);

        scatter_kernel<<<(NE * 32) / 256, 256, 0, stream>>>(x, ei, ew, buf0);

        // t = relu(((1+eps)*x + agg) @ W1 + b1)
        gemm_kernel<0><<<(NN + 31) / 32, 256, 0, stream>>>(x, buf0, W1i, b1i, eps + i, buf1, nullptr);

        // h = t @ W2 + b2 (into buf0), + BN stats
        gemm_kernel<1><<<(NN + 31) / 32, 256, 0, stream>>>(buf1, nullptr, W2i, b2i, nullptr, buf0, stats);

        // x += relu(bn(h))
        bn_apply<<<(n4x + 255) / 256, 256, 0, stream>>>(buf0, stats, gamma + i * DD, beta + i * DD, x);
    }
}

// Round 2
// 1137.597 us; speedup vs baseline: 4.1979x; 4.1979x over previous
//
#include <hip/hip_runtime.h>

#define NN 50000
#define NE 800000
#define DD 128
#define D4 32  // float4s per row

// ---------------- elementwise helpers ----------------

__global__ void copy_f4(const float4* __restrict__ in, float4* __restrict__ out, int n4) {
    int i = blockIdx.x * blockDim.x + threadIdx.x;
    if (i < n4) out[i] = in[i];
}

__global__ void zero_int(int* __restrict__ p, int n) {
    int i = blockIdx.x * blockDim.x + threadIdx.x;
    if (i < n) p[i] = 0;
}

// ---------------- CSR build ----------------

__global__ void hist_kernel(const int* __restrict__ ei, int* __restrict__ counts) {
    int e = blockIdx.x * blockDim.x + threadIdx.x;
    if (e < NE) atomicAdd(&counts[ei[NE + e]], 1);
}

// single block, 256 threads: exclusive scan of counts -> rowptr, and cursor=rowptr
__global__ void scan_kernel(const int* __restrict__ counts, int* __restrict__ rowptr,
                            int* __restrict__ cursor) {
    __shared__ int part[256];
    int tid = threadIdx.x;
    const int CH = (NN + 255) / 256;  // 196
    int beg = tid * CH;
    int end = beg + CH < NN ? beg + CH : NN;
    int s = 0;
    for (int i = beg; i < end; i++) s += counts[i];
    part[tid] = s;
    __syncthreads();
    // Hillis-Steele inclusive scan
    for (int off = 1; off < 256; off <<= 1) {
        int v = part[tid];
        int add = (tid >= off) ? part[tid - off] : 0;
        __syncthreads();
        part[tid] = v + add;
        __syncthreads();
    }
    int run = (tid == 0) ? 0 : part[tid - 1];
    for (int i = beg; i < end; i++) {
        int c = counts[i];
        rowptr[i] = run;
        cursor[i] = run;
        run += c;
    }
    if (tid == 255) rowptr[NN] = run;  // == NE
}

__global__ void fill_kernel(const int* __restrict__ ei, const float* __restrict__ ew,
                            int* __restrict__ cursor, int2* __restrict__ srcw) {
    int e = blockIdx.x * blockDim.x + threadIdx.x;
    if (e >= NE) return;
    int dst = ei[NE + e];
    int idx = atomicAdd(&cursor[dst], 1);
    srcw[idx] = make_int2(ei[e], __float_as_int(ew[e]));
}

// ---------------- gather: agg[n] = sum_{e in CSR[n]} x[src_e] * w_e ----------------
// 32 lanes per node (float4 each), 8 nodes per 256-block. Also zeroes BN stats.

__global__ void __launch_bounds__(256) gather_kernel(
    const float* __restrict__ x, const int2* __restrict__ srcw,
    const int* __restrict__ rowptr, float* __restrict__ agg,
    float* __restrict__ stats) {
    if (blockIdx.x == 0) stats[threadIdx.x] = 0.f;  // 256 floats: sum | sumsq
    int node = blockIdx.x * 8 + (threadIdx.x >> 5);
    int lane = threadIdx.x & 31;
    if (node >= NN) return;
    int beg = rowptr[node], end = rowptr[node + 1];
    float4 acc = make_float4(0.f, 0.f, 0.f, 0.f);
    for (int i = beg; i < end; i++) {
        int2 sw = srcw[i];
        float w = __int_as_float(sw.y);
        float4 v = ((const float4*)x)[sw.x * D4 + lane];
        acc.x += v.x * w; acc.y += v.y * w; acc.z += v.z * w; acc.w += v.w * w;
    }
    ((float4*)agg)[node * D4 + lane] = acc;
}

// ---------------- GEMM: out = act(A' @ W + b) ----------------
// MODE 0: A' = (1+eps)*A + A2, out = relu(..)          (gemm1)
// MODE 1: A' = A, out plain, accumulate col sum/sumsq  (gemm2 + BN stats)
// Block: 32 rows x 128 cols, 256 threads; thread = 4 rows x 4 cols.

template <int MODE>
__global__ void __launch_bounds__(256, 2) gemm_kernel(
    const float* __restrict__ A, const float* __restrict__ A2,
    const float* __restrict__ W, const float* __restrict__ bias,
    const float* __restrict__ epsp, float* __restrict__ out,
    float* __restrict__ stats) {
    __shared__ float4 Ws[4096];  // 128x128 weights, 64 KB
    __shared__ float4 As[1024];  // 32x128 A tile, 16 KB (reused for stat reduce)

    int tid = threadIdx.x;
    int tx = tid & 31;   // col group: cols 4*tx .. 4*tx+3
    int ty = tid >> 5;   // row group: rows ty*4 .. ty*4+3 (within tile)
    int r0 = blockIdx.x * 32;

    // stage W (coalesced)
    const float4* Wg = (const float4*)W;
#pragma unroll
    for (int i = 0; i < 16; i++) Ws[i * 256 + tid] = Wg[i * 256 + tid];

    // stage A tile (with fused GIN input for MODE 0)
    float epsv = (MODE == 0) ? (1.0f + *epsp) : 1.0f;
#pragma unroll
    for (int i = 0; i < 4; i++) {
        int idx = i * 256 + tid;
        int row = idx >> 5;
        int c4 = idx & 31;
        int gr = r0 + row;
        float4 v = make_float4(0.f, 0.f, 0.f, 0.f);
        if (gr < NN) {
            float4 a = ((const float4*)A)[gr * D4 + c4];
            if (MODE == 0) {
                float4 g = ((const float4*)A2)[gr * D4 + c4];
                v = make_float4(a.x * epsv + g.x, a.y * epsv + g.y,
                                a.z * epsv + g.z, a.w * epsv + g.w);
            } else {
                v = a;
            }
        }
        As[idx] = v;
    }
    __syncthreads();

    float4 acc[4];
#pragma unroll
    for (int r = 0; r < 4; r++) acc[r] = make_float4(0.f, 0.f, 0.f, 0.f);

#pragma unroll 8
    for (int kk = 0; kk < 32; kk++) {
        float4 a[4];
#pragma unroll
        for (int r = 0; r < 4; r++) a[r] = As[(ty * 4 + r) * 32 + kk];
        float4 w0 = Ws[(4 * kk + 0) * 32 + tx];
        float4 w1 = Ws[(4 * kk + 1) * 32 + tx];
        float4 w2 = Ws[(4 * kk + 2) * 32 + tx];
        float4 w3 = Ws[(4 * kk + 3) * 32 + tx];
#pragma unroll
        for (int r = 0; r < 4; r++) {
            acc[r].x += a[r].x * w0.x + a[r].y * w1.x + a[r].z * w2.x + a[r].w * w3.x;
            acc[r].y += a[r].x * w0.y + a[r].y * w1.y + a[r].z * w2.y + a[r].w * w3.y;
            acc[r].z += a[r].x * w0.z + a[r].y * w1.z + a[r].z * w2.z + a[r].w * w3.z;
            acc[r].w += a[r].x * w0.w + a[r].y * w1.w + a[r].z * w2.w + a[r].w * w3.w;
        }
    }

    float4 bv = ((const float4*)bias)[tx];
    float4* out4 = (float4*)out;

    if (MODE == 0) {
#pragma unroll
        for (int r = 0; r < 4; r++) {
            int gr = r0 + ty * 4 + r;
            if (gr < NN) {
                float4 v = make_float4(fmaxf(acc[r].x + bv.x, 0.f), fmaxf(acc[r].y + bv.y, 0.f),
                                       fmaxf(acc[r].z + bv.z, 0.f), fmaxf(acc[r].w + bv.w, 0.f));
                out4[gr * D4 + tx] = v;
            }
        }
    } else {
        float4 s = make_float4(0.f, 0.f, 0.f, 0.f);
        float4 s2 = make_float4(0.f, 0.f, 0.f, 0.f);
#pragma unroll
        for (int r = 0; r < 4; r++) {
            int gr = r0 + ty * 4 + r;
            if (gr < NN) {
                float4 v = make_float4(acc[r].x + bv.x, acc[r].y + bv.y,
                                       acc[r].z + bv.z, acc[r].w + bv.w);
                out4[gr * D4 + tx] = v;
                s.x += v.x; s.y += v.y; s.z += v.z; s.w += v.w;
                s2.x += v.x * v.x; s2.y += v.y * v.y; s2.z += v.z * v.z; s2.w += v.w * v.w;
            }
        }
        // cross-ty reduce via As (done reading it), then atomics into stats
        __syncthreads();
        As[ty * 32 + tx] = s;
        __syncthreads();
        if (ty == 0) {
            float4 t = As[tx];
#pragma unroll
            for (int j = 1; j < 8; j++) {
                float4 u = As[j * 32 + tx];
                t.x += u.x; t.y += u.y; t.z += u.z; t.w += u.w;
            }
            atomicAdd(&stats[tx * 4 + 0], t.x);
            atomicAdd(&stats[tx * 4 + 1], t.y);
            atomicAdd(&stats[tx * 4 + 2], t.z);
            atomicAdd(&stats[tx * 4 + 3], t.w);
        }
        __syncthreads();
        As[ty * 32 + tx] = s2;
        __syncthreads();
        if (ty == 0) {
            float4 t = As[tx];
#pragma unroll
            for (int j = 1; j < 8; j++) {
                float4 u = As[j * 32 + tx];
                t.x += u.x; t.y += u.y; t.z += u.z; t.w += u.w;
            }
            atomicAdd(&stats[DD + tx * 4 + 0], t.x);
            atomicAdd(&stats[DD + tx * 4 + 1], t.y);
            atomicAdd(&stats[DD + tx * 4 + 2], t.z);
            atomicAdd(&stats[DD + tx * 4 + 3], t.w);
        }
    }
}

// ---------------- BN apply + ReLU + residual: x += relu(bn(h)) ----------------

__global__ void bn_apply(const float* __restrict__ h, const float* __restrict__ stats,
                         const float* __restrict__ gamma, const float* __restrict__ beta,
                         float* __restrict__ x) {
    int i = blockIdx.x * blockDim.x + threadIdx.x;
    if (i >= NN * D4) return;
    int c4 = i & 31;
    const float invN = 1.0f / NN;
    float4 s = ((const float4*)stats)[c4];
    float4 s2 = ((const float4*)stats)[D4 + c4];
    float4 mu = make_float4(s.x * invN, s.y * invN, s.z * invN, s.w * invN);
    float4 var = make_float4(s2.x * invN - mu.x * mu.x, s2.y * invN - mu.y * mu.y,
                             s2.z * invN - mu.z * mu.z, s2.w * invN - mu.w * mu.w);
    float4 inv = make_float4(rsqrtf(var.x + 1e-5f), rsqrtf(var.y + 1e-5f),
                             rsqrtf(var.z + 1e-5f), rsqrtf(var.w + 1e-5f));
    float4 g = ((const float4*)gamma)[c4];
    float4 b = ((const float4*)beta)[c4];
    float4 hv = ((const float4*)h)[i];
    float4 xv = ((const float4*)x)[i];
    float4 v = make_float4(fmaxf(g.x * (hv.x - mu.x) * inv.x + b.x, 0.f),
                           fmaxf(g.y * (hv.y - mu.y) * inv.y + b.y, 0.f),
                           fmaxf(g.z * (hv.z - mu.z) * inv.z + b.z, 0.f),
                           fmaxf(g.w * (hv.w - mu.w) * inv.w + b.w, 0.f));
    ((float4*)x)[i] = make_float4(xv.x + v.x, xv.y + v.y, xv.z + v.z, xv.w + v.w);
}

// ---------------- launcher ----------------

extern "C" void kernel_launch(void* const* d_in, const int* in_sizes, int n_in,
                              void* d_out, int out_size, void* d_ws, size_t ws_size,
                              hipStream_t stream) {
    const float* x_in = (const float*)d_in[0];
    const int* ei = (const int*)d_in[1];
    // d_in[2] = edge_attr (unused)
    const float* ew = (const float*)d_in[3];
    const float* W1 = (const float*)d_in[4];
    const float* b1 = (const float*)d_in[5];
    const float* W2 = (const float*)d_in[6];
    const float* b2 = (const float*)d_in[7];
    const float* eps = (const float*)d_in[8];
    const float* gamma = (const float*)d_in[9];
    const float* beta = (const float*)d_in[10];

    float* x = (float*)d_out;  // running node features

    char* ws = (char*)d_ws;
    float* buf0 = (float*)ws;                        // agg, then h   (25.6 MB)
    float* buf1 = (float*)(ws + 25600000);           // t             (25.6 MB)
    float* stats = (float*)(ws + 51200000);          // 256 floats (sum | sumsq)
    int* rowptr = (int*)(ws + 51201024);             // 50001 ints
    int* cursor = (int*)(ws + 51401248);             // 50000 ints
    int* counts = (int*)(ws + 51601248);             // 50000 ints
    int2* srcw = (int2*)(ws + 51801248);             // 800000 int2 (src, weight-bits)

    const int n4x = NN * D4;  // 1.6M float4 per node matrix

    // x = x_in
    copy_f4<<<(n4x + 255) / 256, 256, 0, stream>>>((const float4*)x_in, (float4*)x, n4x);

    // ---- CSR build (graph is static across layers) ----
    zero_int<<<(NN + 255) / 256, 256, 0, stream>>>(counts, NN);
    hist_kernel<<<(NE + 255) / 256, 256, 0, stream>>>(ei, counts);
    scan_kernel<<<1, 256, 0, stream>>>(counts, rowptr, cursor);
    fill_kernel<<<(NE + 255) / 256, 256, 0, stream>>>(ei, ew, cursor, srcw);

    for (int i = 0; i < 3; i++) {
        const float* W1i = W1 + i * DD * DD;
        const float* b1i = b1 + i * DD;
        const float* W2i = W2 + i * DD * DD;
        const float* b2i = b2 + i * DD;

        // agg = sum_{edges} x[src]*w  (also zeroes stats)
        gather_kernel<<<(NN + 7) / 8, 256, 0, stream>>>(x, srcw, rowptr, buf0, stats);

        // t = relu(((1+eps)*x + agg) @ W1 + b1)
        gemm_kernel<0><<<(NN + 31) / 32, 256, 0, stream>>>(x, buf0, W1i, b1i, eps + i, buf1, nullptr);

        // h = t @ W2 + b2 (into buf0), + BN stats
        gemm_kernel<1><<<(NN + 31) / 32, 256, 0, stream>>>(buf1, nullptr, W2i, b2i, nullptr, buf0, stats);

        // x += relu(bn(h))
        bn_apply<<<(n4x + 255) / 256, 256, 0, stream>>>(buf0, stats, gamma + i * DD, beta + i * DD, x);
    }
}

// Round 3
// 631.004 us; speedup vs baseline: 7.5681x; 1.8028x over previous
//
#include <hip/hip_runtime.h>

#define NN 50000
#define NE 800000
#define DD 128
#define D4 32  // float4s per row

typedef __attribute__((ext_vector_type(8))) short short8;
typedef __attribute__((ext_vector_type(4))) float f32x4;

__device__ __forceinline__ unsigned short f2bf(float f) {
    unsigned u = __float_as_uint(f);
    unsigned r = u + 0x7FFF + ((u >> 16) & 1);  // RTN-even
    return (unsigned short)(r >> 16);
}

// ---------------- elementwise helpers ----------------

__global__ void copy_f4(const float4* __restrict__ in, float4* __restrict__ out, int n4) {
    int i = blockIdx.x * blockDim.x + threadIdx.x;
    if (i < n4) out[i] = in[i];
}

__global__ void zero_int(int* __restrict__ p, int n) {
    int i = blockIdx.x * blockDim.x + threadIdx.x;
    if (i < n) p[i] = 0;
}

// ---------------- weight prep: Wt[m][n][k] = bf16(W[m][k][n]) ----------------

__global__ void prep_wt(const float* __restrict__ W1, const float* __restrict__ W2,
                        unsigned short* __restrict__ Wt) {
    int i = blockIdx.x * blockDim.x + threadIdx.x;
    if (i >= 6 * 16384) return;
    int m = i >> 14;
    int r = i & 16383;
    int n = r >> 7;
    int k = r & 127;
    const float* Ws = (m < 3) ? (W1 + m * 16384) : (W2 + (m - 3) * 16384);
    Wt[i] = f2bf(Ws[k * 128 + n]);
}

// ---------------- CSR build ----------------

__global__ void hist_kernel(const int* __restrict__ ei, int* __restrict__ counts) {
    int e = blockIdx.x * blockDim.x + threadIdx.x;
    if (e < NE) atomicAdd(&counts[ei[NE + e]], 1);
}

__global__ void scan_kernel(const int* __restrict__ counts, int* __restrict__ rowptr,
                            int* __restrict__ cursor) {
    __shared__ int part[256];
    int tid = threadIdx.x;
    const int CH = (NN + 255) / 256;  // 196
    int beg = tid * CH;
    int end = beg + CH < NN ? beg + CH : NN;
    int s = 0;
    for (int i = beg; i < end; i++) s += counts[i];
    part[tid] = s;
    __syncthreads();
    for (int off = 1; off < 256; off <<= 1) {
        int v = part[tid];
        int add = (tid >= off) ? part[tid - off] : 0;
        __syncthreads();
        part[tid] = v + add;
        __syncthreads();
    }
    int run = (tid == 0) ? 0 : part[tid - 1];
    for (int i = beg; i < end; i++) {
        int c = counts[i];
        rowptr[i] = run;
        cursor[i] = run;
        run += c;
    }
    if (tid == 255) rowptr[NN] = run;
}

__global__ void fill_kernel(const int* __restrict__ ei, const float* __restrict__ ew,
                            int* __restrict__ cursor, int2* __restrict__ srcw) {
    int e = blockIdx.x * blockDim.x + threadIdx.x;
    if (e >= NE) return;
    int dst = ei[NE + e];
    int idx = atomicAdd(&cursor[dst], 1);
    srcw[idx] = make_int2(ei[e], __float_as_int(ew[e]));
}

// ---- gather + GIN combine: g[n] = bf16((1+eps)*x[n] + sum_e w_e * x[src_e]) ----
// 32 lanes per node, 8 nodes per 256-block. Also zeroes BN stats.

__global__ void __launch_bounds__(256) gather_kernel(
    const float* __restrict__ x, const int2* __restrict__ srcw,
    const int* __restrict__ rowptr, const float* __restrict__ epsp,
    unsigned short* __restrict__ g, float* __restrict__ stats) {
    if (blockIdx.x == 0) stats[threadIdx.x] = 0.f;  // 256 floats: sum | sumsq
    int node = blockIdx.x * 8 + (threadIdx.x >> 5);
    int lane = threadIdx.x & 31;
    if (node >= NN) return;
    float epsv = 1.0f + *epsp;
    int beg = rowptr[node], end = rowptr[node + 1];
    float4 xv = ((const float4*)x)[node * D4 + lane];
    float4 acc = make_float4(xv.x * epsv, xv.y * epsv, xv.z * epsv, xv.w * epsv);
    for (int i = beg; i < end; i++) {
        int2 sw = srcw[i];
        float w = __int_as_float(sw.y);
        float4 v = ((const float4*)x)[sw.x * D4 + lane];
        acc.x += v.x * w; acc.y += v.y * w; acc.z += v.z * w; acc.w += v.w * w;
    }
    ushort4 o;
    o.x = f2bf(acc.x); o.y = f2bf(acc.y); o.z = f2bf(acc.z); o.w = f2bf(acc.w);
    ((ushort4*)g)[node * D4 + lane] = o;
}

// ---------------- MFMA GEMM: 128 rows x 128 cols per block, 4 waves ----------------
// Wave w owns cols [w*32, w*32+32): 2 N-tiles of 16; B-frags live in registers.
// A tile staged in LDS, 16B-chunk XOR swizzle (chunk' = chunk ^ (row&15)).
// MODE 0: out = bf16(relu(A@Wt^T + b))    (t)
// MODE 1: out = fp32(A@Wt^T + b), accumulate BN col sums/sumsq into stats.

template <int MODE>
__global__ void __launch_bounds__(256) mfma_gemm(
    const unsigned short* __restrict__ A,   // M x 128 bf16 row-major
    const unsigned short* __restrict__ Wt,  // 128 x 128 bf16, [n][k]
    const float* __restrict__ bias,
    unsigned short* __restrict__ outB, float* __restrict__ outF,
    float* __restrict__ stats) {
    __shared__ unsigned short As[128 * 128];  // 32 KB

    int tid = threadIdx.x;
    int wave = tid >> 6;
    int lane = tid & 63;
    int q = lane >> 4;    // quad 0..3
    int ml = lane & 15;
    int r0 = blockIdx.x * 128;

    // stage A tile (zero-pad rows >= NN)
#pragma unroll
    for (int i = 0; i < 8; i++) {
        int idx = i * 256 + tid;  // 16-B chunk id, 0..2047
        int row = idx >> 4;
        int c = idx & 15;
        float4 v = make_float4(0.f, 0.f, 0.f, 0.f);
        int grow = r0 + row;
        if (grow < NN) v = *(const float4*)(A + grow * DD + c * 8);
        int cs = c ^ (row & 15);
        *(float4*)(&As[row * DD + cs * 8]) = v;
    }

    // B fragments from global (32 KB, L2-resident): lane ml = col n, quad q = k-chunk
    short8 Bf[2][4];
#pragma unroll
    for (int t = 0; t < 2; t++)
#pragma unroll
        for (int ks = 0; ks < 4; ks++) {
            int n = wave * 32 + t * 16 + ml;
            Bf[t][ks] = *(const short8*)(Wt + n * DD + ks * 32 + q * 8);
        }

    float bvl[2] = {bias[wave * 32 + ml], bias[wave * 32 + 16 + ml]};

    __syncthreads();

    float s[2] = {0.f, 0.f}, s2[2] = {0.f, 0.f};

    for (int rt = 0; rt < 8; rt++) {
        int arow = rt * 16 + ml;
        short8 Af[4];
#pragma unroll
        for (int ks = 0; ks < 4; ks++) {
            int cs = (ks * 4 + q) ^ (arow & 15);
            Af[ks] = *(const short8*)(&As[arow * DD + cs * 8]);
        }
        f32x4 acc[2] = {{0.f, 0.f, 0.f, 0.f}, {0.f, 0.f, 0.f, 0.f}};
#pragma unroll
        for (int ks = 0; ks < 4; ks++) {
            acc[0] = __builtin_amdgcn_mfma_f32_16x16x32_bf16(Af[ks], Bf[0][ks], acc[0], 0, 0, 0);
            acc[1] = __builtin_amdgcn_mfma_f32_16x16x32_bf16(Af[ks], Bf[1][ks], acc[1], 0, 0, 0);
        }
        // epilogue: C/D layout col=lane&15, row=quad*4+reg  [m89-verified]
#pragma unroll
        for (int t = 0; t < 2; t++) {
            int col = wave * 32 + t * 16 + ml;
#pragma unroll
            for (int r = 0; r < 4; r++) {
                int grow = r0 + rt * 16 + q * 4 + r;
                if (grow < NN) {
                    float v = acc[t][r] + bvl[t];
                    if (MODE == 0) {
                        outB[grow * DD + col] = f2bf(fmaxf(v, 0.f));
                    } else {
                        outF[grow * DD + col] = v;
                        s[t] += v;
                        s2[t] += v * v;
                    }
                }
            }
        }
    }

    if (MODE == 1) {
        // lanes {ml, ml+16, ml+32, ml+48} share a column -> reduce over q, then atomics
#pragma unroll
        for (int t = 0; t < 2; t++) {
            float a = s[t], b = s2[t];
            a += __shfl_xor(a, 16); b += __shfl_xor(b, 16);
            a += __shfl_xor(a, 32); b += __shfl_xor(b, 32);
            if (q == 0) {
                int col = wave * 32 + t * 16 + ml;
                atomicAdd(&stats[col], a);
                atomicAdd(&stats[DD + col], b);
            }
        }
    }
}

// ---------------- BN apply + ReLU + residual: x += relu(bn(h)) ----------------

__global__ void bn_apply(const float* __restrict__ h, const float* __restrict__ stats,
                         const float* __restrict__ gamma, const float* __restrict__ beta,
                         float* __restrict__ x) {
    int i = blockIdx.x * blockDim.x + threadIdx.x;
    if (i >= NN * D4) return;
    int c4 = i & 31;
    const float invN = 1.0f / NN;
    float4 s = ((const float4*)stats)[c4];
    float4 s2 = ((const float4*)stats)[D4 + c4];
    float4 mu = make_float4(s.x * invN, s.y * invN, s.z * invN, s.w * invN);
    float4 var = make_float4(s2.x * invN - mu.x * mu.x, s2.y * invN - mu.y * mu.y,
                             s2.z * invN - mu.z * mu.z, s2.w * invN - mu.w * mu.w);
    float4 inv = make_float4(rsqrtf(var.x + 1e-5f), rsqrtf(var.y + 1e-5f),
                             rsqrtf(var.z + 1e-5f), rsqrtf(var.w + 1e-5f));
    float4 g = ((const float4*)gamma)[c4];
    float4 b = ((const float4*)beta)[c4];
    float4 hv = ((const float4*)h)[i];
    float4 xv = ((const float4*)x)[i];
    float4 v = make_float4(fmaxf(g.x * (hv.x - mu.x) * inv.x + b.x, 0.f),
                           fmaxf(g.y * (hv.y - mu.y) * inv.y + b.y, 0.f),
                           fmaxf(g.z * (hv.z - mu.z) * inv.z + b.z, 0.f),
                           fmaxf(g.w * (hv.w - mu.w) * inv.w + b.w, 0.f));
    ((float4*)x)[i] = make_float4(xv.x + v.x, xv.y + v.y, xv.z + v.z, xv.w + v.w);
}

// ---------------- launcher ----------------

extern "C" void kernel_launch(void* const* d_in, const int* in_sizes, int n_in,
                              void* d_out, int out_size, void* d_ws, size_t ws_size,
                              hipStream_t stream) {
    const float* x_in = (const float*)d_in[0];
    const int* ei = (const int*)d_in[1];
    // d_in[2] = edge_attr (unused)
    const float* ew = (const float*)d_in[3];
    const float* W1 = (const float*)d_in[4];
    const float* b1 = (const float*)d_in[5];
    const float* W2 = (const float*)d_in[6];
    const float* b2 = (const float*)d_in[7];
    const float* eps = (const float*)d_in[8];
    const float* gamma = (const float*)d_in[9];
    const float* beta = (const float*)d_in[10];

    float* x = (float*)d_out;  // running node features

    char* ws = (char*)d_ws;
    float* hbuf = (float*)ws;                              // h fp32        (25.6 MB)
    unsigned short* g = (unsigned short*)(ws + 25600000);  // GIN input bf16 (12.8 MB)
    unsigned short* t = (unsigned short*)(ws + 38400000);  // MLP mid bf16   (12.8 MB)
    float* stats = (float*)(ws + 51200000);                // 256 floats (sum | sumsq)
    int* rowptr = (int*)(ws + 51201024);                   // 50001 ints
    int* cursor = (int*)(ws + 51401056);                   // 50000 ints
    int* counts = (int*)(ws + 51601056);                   // 50000 ints; later reused as Wt
    unsigned short* Wtall = (unsigned short*)(ws + 51601056);  // 6*16384 bf16 (reuses counts)
    int2* srcw = (int2*)(ws + 51801056);                   // 800000 int2 (src, weight-bits)

    const int n4x = NN * D4;

    // x = x_in
    copy_f4<<<(n4x + 255) / 256, 256, 0, stream>>>((const float4*)x_in, (float4*)x, n4x);

    // ---- CSR build (graph static across layers) ----
    zero_int<<<(NN + 255) / 256, 256, 0, stream>>>(counts, NN);
    hist_kernel<<<(NE + 255) / 256, 256, 0, stream>>>(ei, counts);
    scan_kernel<<<1, 256, 0, stream>>>(counts, rowptr, cursor);
    fill_kernel<<<(NE + 255) / 256, 256, 0, stream>>>(ei, ew, cursor, srcw);

    // ---- weights -> bf16 transposed (counts is dead now; Wtall overlays it) ----
    prep_wt<<<(6 * 16384 + 255) / 256, 256, 0, stream>>>(W1, W2, Wtall);

    const int gemmGrid = (NN + 127) / 128;  // 391

    for (int i = 0; i < 3; i++) {
        const float* b1i = b1 + i * DD;
        const float* b2i = b2 + i * DD;
        const unsigned short* Wt1 = Wtall + i * 16384;
        const unsigned short* Wt2 = Wtall + (3 + i) * 16384;

        // g = bf16((1+eps)*x + agg); zeroes stats
        gather_kernel<<<(NN + 7) / 8, 256, 0, stream>>>(x, srcw, rowptr, eps + i, g, stats);

        // t = bf16(relu(g @ W1 + b1))
        mfma_gemm<0><<<gemmGrid, 256, 0, stream>>>(g, Wt1, b1i, t, nullptr, nullptr);

        // h = t @ W2 + b2 (fp32), + BN stats
        mfma_gemm<1><<<gemmGrid, 256, 0, stream>>>(t, Wt2, b2i, nullptr, hbuf, stats);

        // x += relu(bn(h))
        bn_apply<<<(n4x + 255) / 256, 256, 0, stream>>>(hbuf, stats, gamma + i * DD, beta + i * DD, x);
    }
}

// Round 4
// 512.800 us; speedup vs baseline: 9.3126x; 1.2305x over previous
//
#include <hip/hip_runtime.h>

#define NN 50000
#define NE 800000
#define DD 128
#define D4 32       // float4s per row
#define SCAN_NB 196 // ceil(NN/256)

typedef __attribute__((ext_vector_type(8))) short short8;
typedef __attribute__((ext_vector_type(4))) float f32x4;

__device__ __forceinline__ unsigned short f2bf(float f) {
    unsigned u = __float_as_uint(f);
    unsigned r = u + 0x7FFF + ((u >> 16) & 1);  // RTN-even
    return (unsigned short)(r >> 16);
}

// ---------------- elementwise helpers ----------------

__global__ void zero_int(int* __restrict__ p, int n) {
    int i = blockIdx.x * blockDim.x + threadIdx.x;
    if (i < n) p[i] = 0;
}

// ---------------- weight prep: Wt[m][n][k] = bf16(W[m][k][n]) ----------------

__global__ void prep_wt(const float* __restrict__ W1, const float* __restrict__ W2,
                        unsigned short* __restrict__ Wt) {
    int i = blockIdx.x * blockDim.x + threadIdx.x;
    if (i >= 6 * 16384) return;
    int m = i >> 14;
    int r = i & 16383;
    int n = r >> 7;
    int k = r & 127;
    const float* Ws = (m < 3) ? (W1 + m * 16384) : (W2 + (m - 3) * 16384);
    Wt[i] = f2bf(Ws[k * 128 + n]);
}

// ---------------- CSR build ----------------

__global__ void hist_kernel(const int* __restrict__ ei, int* __restrict__ counts) {
    int e = blockIdx.x * blockDim.x + threadIdx.x;
    if (e < NE) atomicAdd(&counts[ei[NE + e]], 1);
}

// pass 1: per-block sums of counts
__global__ void block_sums(const int* __restrict__ counts, int* __restrict__ bsum) {
    int i = blockIdx.x * 256 + threadIdx.x;
    int v = (i < NN) ? counts[i] : 0;
#pragma unroll
    for (int off = 1; off < 64; off <<= 1) v += __shfl_xor(v, off);
    __shared__ int wsum[4];
    if ((threadIdx.x & 63) == 0) wsum[threadIdx.x >> 6] = v;
    __syncthreads();
    if (threadIdx.x == 0) bsum[blockIdx.x] = wsum[0] + wsum[1] + wsum[2] + wsum[3];
}

// pass 2: exclusive scan of the 196 block sums (1 block, all-LDS)
__global__ void scan_bsums(const int* __restrict__ bsum, int* __restrict__ bbase) {
    __shared__ int sh[256];
    int tid = threadIdx.x;
    sh[tid] = (tid < SCAN_NB) ? bsum[tid] : 0;
    __syncthreads();
    for (int off = 1; off < 256; off <<= 1) {
        int add = (tid >= off) ? sh[tid - off] : 0;
        __syncthreads();
        sh[tid] += add;
        __syncthreads();
    }
    if (tid < SCAN_NB) bbase[tid] = (tid == 0) ? 0 : sh[tid - 1];
}

// pass 3: intra-block exclusive scan + base -> rowptr, cursor
__global__ void rowptr_fill(const int* __restrict__ counts, const int* __restrict__ bbase,
                            int* __restrict__ rowptr, int* __restrict__ cursor) {
    __shared__ int sh[256];
    int tid = threadIdx.x;
    int i = blockIdx.x * 256 + tid;
    int c = (i < NN) ? counts[i] : 0;
    sh[tid] = c;
    __syncthreads();
    for (int off = 1; off < 256; off <<= 1) {
        int add = (tid >= off) ? sh[tid - off] : 0;
        __syncthreads();
        sh[tid] += add;
        __syncthreads();
    }
    int excl = bbase[blockIdx.x] + sh[tid] - c;
    if (i < NN) {
        rowptr[i] = excl;
        cursor[i] = excl;
        if (i == NN - 1) rowptr[NN] = excl + c;  // == NE
    }
}

__global__ void fill_kernel(const int* __restrict__ ei, const float* __restrict__ ew,
                            int* __restrict__ cursor, int2* __restrict__ srcw) {
    int e = blockIdx.x * blockDim.x + threadIdx.x;
    if (e >= NE) return;
    int dst = ei[NE + e];
    int idx = atomicAdd(&cursor[dst], 1);
    srcw[idx] = make_int2(ei[e], __float_as_int(ew[e]));
}

// ---- gather + GIN combine: g[n] = bf16((1+eps)*xsrc[n] + sum_e w_e * xsrc[src_e]) ----
// 32 lanes per node, 8 nodes per 256-block. Also zeroes BN stats.

__global__ void __launch_bounds__(256) gather_kernel(
    const float* __restrict__ xsrc, const int2* __restrict__ srcw,
    const int* __restrict__ rowptr, const float* __restrict__ epsp,
    unsigned short* __restrict__ g, float* __restrict__ stats) {
    if (blockIdx.x == 0) stats[threadIdx.x] = 0.f;  // 256 floats: sum | sumsq
    int node = blockIdx.x * 8 + (threadIdx.x >> 5);
    int lane = threadIdx.x & 31;
    if (node >= NN) return;
    float epsv = 1.0f + *epsp;
    int beg = rowptr[node], end = rowptr[node + 1];
    float4 xv = ((const float4*)xsrc)[node * D4 + lane];
    float4 acc = make_float4(xv.x * epsv, xv.y * epsv, xv.z * epsv, xv.w * epsv);
    for (int i = beg; i < end; i++) {
        int2 sw = srcw[i];
        float w = __int_as_float(sw.y);
        float4 v = ((const float4*)xsrc)[sw.x * D4 + lane];
        acc.x += v.x * w; acc.y += v.y * w; acc.z += v.z * w; acc.w += v.w * w;
    }
    ushort4 o;
    o.x = f2bf(acc.x); o.y = f2bf(acc.y); o.z = f2bf(acc.z); o.w = f2bf(acc.w);
    ((ushort4*)g)[node * D4 + lane] = o;
}

// ---------------- MFMA GEMM: 128 rows x 128 cols per block, 4 waves ----------------
// Wave w owns cols [w*32, w*32+32): 2 N-tiles of 16; B-frags live in registers.
// A tile staged in LDS, 16B-chunk XOR swizzle (chunk' = chunk ^ (row&15)).
// MODE 0: out = bf16(relu(A@Wt^T + b))    (t)
// MODE 1: out = fp32(A@Wt^T + b), accumulate BN col sums/sumsq into stats.

template <int MODE>
__global__ void __launch_bounds__(256) mfma_gemm(
    const unsigned short* __restrict__ A,   // M x 128 bf16 row-major
    const unsigned short* __restrict__ Wt,  // 128 x 128 bf16, [n][k]
    const float* __restrict__ bias,
    unsigned short* __restrict__ outB, float* __restrict__ outF,
    float* __restrict__ stats) {
    __shared__ unsigned short As[128 * 128];  // 32 KB

    int tid = threadIdx.x;
    int wave = tid >> 6;
    int lane = tid & 63;
    int q = lane >> 4;    // quad 0..3
    int ml = lane & 15;
    int r0 = blockIdx.x * 128;

    // stage A tile (zero-pad rows >= NN)
#pragma unroll
    for (int i = 0; i < 8; i++) {
        int idx = i * 256 + tid;  // 16-B chunk id, 0..2047
        int row = idx >> 4;
        int c = idx & 15;
        float4 v = make_float4(0.f, 0.f, 0.f, 0.f);
        int grow = r0 + row;
        if (grow < NN) v = *(const float4*)(A + grow * DD + c * 8);
        int cs = c ^ (row & 15);
        *(float4*)(&As[row * DD + cs * 8]) = v;
    }

    // B fragments from global (32 KB, L2-resident): lane ml = col n, quad q = k-chunk
    short8 Bf[2][4];
#pragma unroll
    for (int t = 0; t < 2; t++)
#pragma unroll
        for (int ks = 0; ks < 4; ks++) {
            int n = wave * 32 + t * 16 + ml;
            Bf[t][ks] = *(const short8*)(Wt + n * DD + ks * 32 + q * 8);
        }

    float bvl[2] = {bias[wave * 32 + ml], bias[wave * 32 + 16 + ml]};

    __syncthreads();

    float s[2] = {0.f, 0.f}, s2[2] = {0.f, 0.f};

    for (int rt = 0; rt < 8; rt++) {
        int arow = rt * 16 + ml;
        short8 Af[4];
#pragma unroll
        for (int ks = 0; ks < 4; ks++) {
            int cs = (ks * 4 + q) ^ (arow & 15);
            Af[ks] = *(const short8*)(&As[arow * DD + cs * 8]);
        }
        f32x4 acc[2] = {{0.f, 0.f, 0.f, 0.f}, {0.f, 0.f, 0.f, 0.f}};
#pragma unroll
        for (int ks = 0; ks < 4; ks++) {
            acc[0] = __builtin_amdgcn_mfma_f32_16x16x32_bf16(Af[ks], Bf[0][ks], acc[0], 0, 0, 0);
            acc[1] = __builtin_amdgcn_mfma_f32_16x16x32_bf16(Af[ks], Bf[1][ks], acc[1], 0, 0, 0);
        }
        // epilogue: C/D layout col=lane&15, row=quad*4+reg  [m89-verified]
#pragma unroll
        for (int t = 0; t < 2; t++) {
            int col = wave * 32 + t * 16 + ml;
#pragma unroll
            for (int r = 0; r < 4; r++) {
                int grow = r0 + rt * 16 + q * 4 + r;
                if (grow < NN) {
                    float v = acc[t][r] + bvl[t];
                    if (MODE == 0) {
                        outB[grow * DD + col] = f2bf(fmaxf(v, 0.f));
                    } else {
                        outF[grow * DD + col] = v;
                        s[t] += v;
                        s2[t] += v * v;
                    }
                }
            }
        }
    }

    if (MODE == 1) {
        // lanes {ml, ml+16, ml+32, ml+48} share a column -> reduce over q, then atomics
#pragma unroll
        for (int t = 0; t < 2; t++) {
            float a = s[t], b = s2[t];
            a += __shfl_xor(a, 16); b += __shfl_xor(b, 16);
            a += __shfl_xor(a, 32); b += __shfl_xor(b, 32);
            if (q == 0) {
                int col = wave * 32 + t * 16 + ml;
                atomicAdd(&stats[col], a);
                atomicAdd(&stats[DD + col], b);
            }
        }
    }
}

// ---------------- BN apply + ReLU + residual: x = xin + relu(bn(h)) ----------------

__global__ void bn_apply(const float* __restrict__ h, const float* __restrict__ stats,
                         const float* __restrict__ gamma, const float* __restrict__ beta,
                         const float* __restrict__ xin, float* __restrict__ x) {
    int i = blockIdx.x * blockDim.x + threadIdx.x;
    if (i >= NN * D4) return;
    int c4 = i & 31;
    const float invN = 1.0f / NN;
    float4 s = ((const float4*)stats)[c4];
    float4 s2 = ((const float4*)stats)[D4 + c4];
    float4 mu = make_float4(s.x * invN, s.y * invN, s.z * invN, s.w * invN);
    float4 var = make_float4(s2.x * invN - mu.x * mu.x, s2.y * invN - mu.y * mu.y,
                             s2.z * invN - mu.z * mu.z, s2.w * invN - mu.w * mu.w);
    float4 inv = make_float4(rsqrtf(var.x + 1e-5f), rsqrtf(var.y + 1e-5f),
                             rsqrtf(var.z + 1e-5f), rsqrtf(var.w + 1e-5f));
    float4 g = ((const float4*)gamma)[c4];
    float4 b = ((const float4*)beta)[c4];
    float4 hv = ((const float4*)h)[i];
    float4 xv = ((const float4*)xin)[i];
    float4 v = make_float4(fmaxf(g.x * (hv.x - mu.x) * inv.x + b.x, 0.f),
                           fmaxf(g.y * (hv.y - mu.y) * inv.y + b.y, 0.f),
                           fmaxf(g.z * (hv.z - mu.z) * inv.z + b.z, 0.f),
                           fmaxf(g.w * (hv.w - mu.w) * inv.w + b.w, 0.f));
    ((float4*)x)[i] = make_float4(xv.x + v.x, xv.y + v.y, xv.z + v.z, xv.w + v.w);
}

// ---------------- launcher ----------------

extern "C" void kernel_launch(void* const* d_in, const int* in_sizes, int n_in,
                              void* d_out, int out_size, void* d_ws, size_t ws_size,
                              hipStream_t stream) {
    const float* x_in = (const float*)d_in[0];
    const int* ei = (const int*)d_in[1];
    // d_in[2] = edge_attr (unused)
    const float* ew = (const float*)d_in[3];
    const float* W1 = (const float*)d_in[4];
    const float* b1 = (const float*)d_in[5];
    const float* W2 = (const float*)d_in[6];
    const float* b2 = (const float*)d_in[7];
    const float* eps = (const float*)d_in[8];
    const float* gamma = (const float*)d_in[9];
    const float* beta = (const float*)d_in[10];

    float* x = (float*)d_out;  // running node features

    char* ws = (char*)d_ws;
    float* hbuf = (float*)ws;                              // h fp32         (25.6 MB)
    unsigned short* g = (unsigned short*)(ws + 25600000);  // GIN input bf16 (12.8 MB)
    unsigned short* t = (unsigned short*)(ws + 38400000);  // MLP mid bf16   (12.8 MB)
    float* stats = (float*)(ws + 51200000);                // 256 floats (sum | sumsq)
    int* rowptr = (int*)(ws + 51201024);                   // 50001 ints
    int* cursor = (int*)(ws + 51401056);                   // 50000 ints
    int* counts = (int*)(ws + 51601056);                   // 50000 ints; later reused as Wt
    unsigned short* Wtall = (unsigned short*)(ws + 51601056);  // 6*16384 bf16 (overlays counts)
    int2* srcw = (int2*)(ws + 51801056);                   // 800000 int2 (src, weight-bits)
    int* bsum = (int*)(ws + 58201056);                     // 196 ints
    int* bbase = (int*)(ws + 58202080);                    // 196 ints

    const int n4x = NN * D4;

    // ---- CSR build (graph static across layers) ----
    zero_int<<<(NN + 255) / 256, 256, 0, stream>>>(counts, NN);
    hist_kernel<<<(NE + 255) / 256, 256, 0, stream>>>(ei, counts);
    block_sums<<<SCAN_NB, 256, 0, stream>>>(counts, bsum);
    scan_bsums<<<1, 256, 0, stream>>>(bsum, bbase);
    rowptr_fill<<<SCAN_NB, 256, 0, stream>>>(counts, bbase, rowptr, cursor);
    fill_kernel<<<(NE + 255) / 256, 256, 0, stream>>>(ei, ew, cursor, srcw);

    // ---- weights -> bf16 transposed (counts is dead after rowptr_fill... but Wtall
    //      overlays counts, so prep AFTER the scan passes) ----
    prep_wt<<<(6 * 16384 + 255) / 256, 256, 0, stream>>>(W1, W2, Wtall);

    const int gemmGrid = (NN + 127) / 128;  // 391

    for (int i = 0; i < 3; i++) {
        const float* b1i = b1 + i * DD;
        const float* b2i = b2 + i * DD;
        const unsigned short* Wt1 = Wtall + i * 16384;
        const unsigned short* Wt2 = Wtall + (3 + i) * 16384;
        const float* xsrc = (i == 0) ? x_in : x;

        // g = bf16((1+eps)*xsrc + agg); zeroes stats
        gather_kernel<<<(NN + 7) / 8, 256, 0, stream>>>(xsrc, srcw, rowptr, eps + i, g, stats);

        // t = bf16(relu(g @ W1 + b1))
        mfma_gemm<0><<<gemmGrid, 256, 0, stream>>>(g, Wt1, b1i, t, nullptr, nullptr);

        // h = t @ W2 + b2 (fp32), + BN stats
        mfma_gemm<1><<<gemmGrid, 256, 0, stream>>>(t, Wt2, b2i, nullptr, hbuf, stats);

        // x = xsrc + relu(bn(h))
        bn_apply<<<(n4x + 255) / 256, 256, 0, stream>>>(hbuf, stats, gamma + i * DD,
                                                        beta + i * DD, xsrc, x);
    }
}

// Round 5
// 445.753 us; speedup vs baseline: 10.7134x; 1.1504x over previous
//
#include <hip/hip_runtime.h>

#define NN 50000
#define NE 800000
#define DD 128
#define D4 32       // float4s per row
#define SCAN_NB 196 // ceil(NN/256)

typedef __attribute__((ext_vector_type(8))) short short8;
typedef __attribute__((ext_vector_type(4))) float f32x4;

__device__ __forceinline__ unsigned short f2bf(float f) {
    unsigned u = __float_as_uint(f);
    unsigned r = u + 0x7FFF + ((u >> 16) & 1);  // RTN-even
    return (unsigned short)(r >> 16);
}
__device__ __forceinline__ float bf2f(unsigned short s) {
    return __uint_as_float(((unsigned)s) << 16);
}

// ---------------- elementwise helpers ----------------

__global__ void zero_int(int* __restrict__ p, int n) {
    int i = blockIdx.x * blockDim.x + threadIdx.x;
    if (i < n) p[i] = 0;
}

// xb = bf16(x_in), 4 elems/thread
__global__ void x2b(const float4* __restrict__ xin, ushort4* __restrict__ xb) {
    int i = blockIdx.x * blockDim.x + threadIdx.x;
    if (i >= NN * D4) return;
    float4 v = xin[i];
    ushort4 o;
    o.x = f2bf(v.x); o.y = f2bf(v.y); o.z = f2bf(v.z); o.w = f2bf(v.w);
    xb[i] = o;
}

// ---------------- weight prep: Wt[m][n][k] = bf16(W[m][k][n]) ----------------

__global__ void prep_wt(const float* __restrict__ W1, const float* __restrict__ W2,
                        unsigned short* __restrict__ Wt) {
    int i = blockIdx.x * blockDim.x + threadIdx.x;
    if (i >= 6 * 16384) return;
    int m = i >> 14;
    int r = i & 16383;
    int n = r >> 7;
    int k = r & 127;
    const float* Ws = (m < 3) ? (W1 + m * 16384) : (W2 + (m - 3) * 16384);
    Wt[i] = f2bf(Ws[k * 128 + n]);
}

// ---------------- CSR build ----------------

__global__ void hist_kernel(const int* __restrict__ ei, int* __restrict__ counts) {
    int e = blockIdx.x * blockDim.x + threadIdx.x;
    if (e < NE) atomicAdd(&counts[ei[NE + e]], 1);
}

__global__ void block_sums(const int* __restrict__ counts, int* __restrict__ bsum) {
    int i = blockIdx.x * 256 + threadIdx.x;
    int v = (i < NN) ? counts[i] : 0;
#pragma unroll
    for (int off = 1; off < 64; off <<= 1) v += __shfl_xor(v, off);
    __shared__ int wsum[4];
    if ((threadIdx.x & 63) == 0) wsum[threadIdx.x >> 6] = v;
    __syncthreads();
    if (threadIdx.x == 0) bsum[blockIdx.x] = wsum[0] + wsum[1] + wsum[2] + wsum[3];
}

__global__ void scan_bsums(const int* __restrict__ bsum, int* __restrict__ bbase) {
    __shared__ int sh[256];
    int tid = threadIdx.x;
    sh[tid] = (tid < SCAN_NB) ? bsum[tid] : 0;
    __syncthreads();
    for (int off = 1; off < 256; off <<= 1) {
        int add = (tid >= off) ? sh[tid - off] : 0;
        __syncthreads();
        sh[tid] += add;
        __syncthreads();
    }
    if (tid < SCAN_NB) bbase[tid] = (tid == 0) ? 0 : sh[tid - 1];
}

__global__ void rowptr_fill(const int* __restrict__ counts, const int* __restrict__ bbase,
                            int* __restrict__ rowptr, int* __restrict__ cursor) {
    __shared__ int sh[256];
    int tid = threadIdx.x;
    int i = blockIdx.x * 256 + tid;
    int c = (i < NN) ? counts[i] : 0;
    sh[tid] = c;
    __syncthreads();
    for (int off = 1; off < 256; off <<= 1) {
        int add = (tid >= off) ? sh[tid - off] : 0;
        __syncthreads();
        sh[tid] += add;
        __syncthreads();
    }
    int excl = bbase[blockIdx.x] + sh[tid] - c;
    if (i < NN) {
        rowptr[i] = excl;
        cursor[i] = excl;
        if (i == NN - 1) rowptr[NN] = excl + c;  // == NE
    }
}

__global__ void fill_kernel(const int* __restrict__ ei, const float* __restrict__ ew,
                            int* __restrict__ cursor, int2* __restrict__ srcw) {
    int e = blockIdx.x * blockDim.x + threadIdx.x;
    if (e >= NE) return;
    int dst = ei[NE + e];
    int idx = atomicAdd(&cursor[dst], 1);
    srcw[idx] = make_int2(ei[e], __float_as_int(ew[e]));
}

// ---- gather + GIN combine: g[n] = bf16((1+eps)*x[n] + sum_e w_e * xb[src_e]) ----
// 32 lanes per node (8 B of bf16 row each), 8 nodes per 256-block.
// 2-way unrolled edge loop for memory-level parallelism. Also zeroes BN stats.

__global__ void __launch_bounds__(256) gather_kernel(
    const unsigned short* __restrict__ xb, const int2* __restrict__ srcw,
    const int* __restrict__ rowptr, const float* __restrict__ epsp,
    unsigned short* __restrict__ g, float* __restrict__ stats) {
    if (blockIdx.x == 0) stats[threadIdx.x] = 0.f;  // 256 floats: sum | sumsq
    int node = blockIdx.x * 8 + (threadIdx.x >> 5);
    int lane = threadIdx.x & 31;
    if (node >= NN) return;
    float epsv = 1.0f + *epsp;
    int beg = rowptr[node], end = rowptr[node + 1];
    const ushort4* xb4 = (const ushort4*)xb;
    ushort4 xv = xb4[node * D4 + lane];
    float4 acc = make_float4(bf2f(xv.x) * epsv, bf2f(xv.y) * epsv,
                             bf2f(xv.z) * epsv, bf2f(xv.w) * epsv);
    int i = beg;
    for (; i + 1 < end; i += 2) {
        int2 sw0 = srcw[i];
        int2 sw1 = srcw[i + 1];
        ushort4 r0 = xb4[sw0.x * D4 + lane];
        ushort4 r1 = xb4[sw1.x * D4 + lane];
        float w0 = __int_as_float(sw0.y);
        float w1 = __int_as_float(sw1.y);
        acc.x += bf2f(r0.x) * w0; acc.y += bf2f(r0.y) * w0;
        acc.z += bf2f(r0.z) * w0; acc.w += bf2f(r0.w) * w0;
        acc.x += bf2f(r1.x) * w1; acc.y += bf2f(r1.y) * w1;
        acc.z += bf2f(r1.z) * w1; acc.w += bf2f(r1.w) * w1;
    }
    if (i < end) {
        int2 sw = srcw[i];
        ushort4 r = xb4[sw.x * D4 + lane];
        float w = __int_as_float(sw.y);
        acc.x += bf2f(r.x) * w; acc.y += bf2f(r.y) * w;
        acc.z += bf2f(r.z) * w; acc.w += bf2f(r.w) * w;
    }
    ushort4 o;
    o.x = f2bf(acc.x); o.y = f2bf(acc.y); o.z = f2bf(acc.z); o.w = f2bf(acc.w);
    ((ushort4*)g)[node * D4 + lane] = o;
}

// ---------------- MFMA GEMM: 128 rows x 128 cols per block, 4 waves ----------------
// MODE 0: out = bf16(relu(A@Wt^T + b))                        (t)
// MODE 1: out = bf16(A@Wt^T + b), BN col sums/sumsq -> stats  (h)

template <int MODE>
__global__ void __launch_bounds__(256) mfma_gemm(
    const unsigned short* __restrict__ A,   // M x 128 bf16 row-major
    const unsigned short* __restrict__ Wt,  // 128 x 128 bf16, [n][k]
    const float* __restrict__ bias,
    unsigned short* __restrict__ outB, float* __restrict__ stats) {
    __shared__ unsigned short As[128 * 128];  // 32 KB

    int tid = threadIdx.x;
    int wave = tid >> 6;
    int lane = tid & 63;
    int q = lane >> 4;    // quad 0..3
    int ml = lane & 15;
    int r0 = blockIdx.x * 128;

    // stage A tile (zero-pad rows >= NN), 16B-chunk XOR swizzle
#pragma unroll
    for (int i = 0; i < 8; i++) {
        int idx = i * 256 + tid;  // chunk id 0..2047
        int row = idx >> 4;
        int c = idx & 15;
        float4 v = make_float4(0.f, 0.f, 0.f, 0.f);
        int grow = r0 + row;
        if (grow < NN) v = *(const float4*)(A + grow * DD + c * 8);
        int cs = c ^ (row & 15);
        *(float4*)(&As[row * DD + cs * 8]) = v;
    }

    // B fragments from global (32 KB, L2-resident)
    short8 Bf[2][4];
#pragma unroll
    for (int t = 0; t < 2; t++)
#pragma unroll
        for (int ks = 0; ks < 4; ks++) {
            int n = wave * 32 + t * 16 + ml;
            Bf[t][ks] = *(const short8*)(Wt + n * DD + ks * 32 + q * 8);
        }

    float bvl[2] = {bias[wave * 32 + ml], bias[wave * 32 + 16 + ml]};

    __syncthreads();

    float s[2] = {0.f, 0.f}, s2[2] = {0.f, 0.f};

    for (int rt = 0; rt < 8; rt++) {
        int arow = rt * 16 + ml;
        short8 Af[4];
#pragma unroll
        for (int ks = 0; ks < 4; ks++) {
            int cs = (ks * 4 + q) ^ (arow & 15);
            Af[ks] = *(const short8*)(&As[arow * DD + cs * 8]);
        }
        f32x4 acc[2] = {{0.f, 0.f, 0.f, 0.f}, {0.f, 0.f, 0.f, 0.f}};
#pragma unroll
        for (int ks = 0; ks < 4; ks++) {
            acc[0] = __builtin_amdgcn_mfma_f32_16x16x32_bf16(Af[ks], Bf[0][ks], acc[0], 0, 0, 0);
            acc[1] = __builtin_amdgcn_mfma_f32_16x16x32_bf16(Af[ks], Bf[1][ks], acc[1], 0, 0, 0);
        }
        // epilogue: C/D layout col=lane&15, row=quad*4+reg  [m89-verified]
#pragma unroll
        for (int t = 0; t < 2; t++) {
            int col = wave * 32 + t * 16 + ml;
#pragma unroll
            for (int r = 0; r < 4; r++) {
                int grow = r0 + rt * 16 + q * 4 + r;
                if (grow < NN) {
                    float v = acc[t][r] + bvl[t];
                    if (MODE == 0) {
                        outB[grow * DD + col] = f2bf(fmaxf(v, 0.f));
                    } else {
                        outB[grow * DD + col] = f2bf(v);
                        s[t] += v;
                        s2[t] += v * v;
                    }
                }
            }
        }
    }

    if (MODE == 1) {
#pragma unroll
        for (int t = 0; t < 2; t++) {
            float a = s[t], b = s2[t];
            a += __shfl_xor(a, 16); b += __shfl_xor(b, 16);
            a += __shfl_xor(a, 32); b += __shfl_xor(b, 32);
            if (q == 0) {
                int col = wave * 32 + t * 16 + ml;
                atomicAdd(&stats[col], a);
                atomicAdd(&stats[DD + col], b);
            }
        }
    }
}

// -------- BN apply + ReLU + residual: x = xin + relu(bn(h)); xb = bf16(x) --------

__global__ void bn_apply(const unsigned short* __restrict__ hb, const float* __restrict__ stats,
                         const float* __restrict__ gamma, const float* __restrict__ beta,
                         const float* __restrict__ xin, float* __restrict__ x,
                         ushort4* __restrict__ xbout) {
    int i = blockIdx.x * blockDim.x + threadIdx.x;
    if (i >= NN * D4) return;
    int c4 = i & 31;
    const float invN = 1.0f / NN;
    float4 s = ((const float4*)stats)[c4];
    float4 s2 = ((const float4*)stats)[D4 + c4];
    float4 mu = make_float4(s.x * invN, s.y * invN, s.z * invN, s.w * invN);
    float4 var = make_float4(s2.x * invN - mu.x * mu.x, s2.y * invN - mu.y * mu.y,
                             s2.z * invN - mu.z * mu.z, s2.w * invN - mu.w * mu.w);
    float4 inv = make_float4(rsqrtf(var.x + 1e-5f), rsqrtf(var.y + 1e-5f),
                             rsqrtf(var.z + 1e-5f), rsqrtf(var.w + 1e-5f));
    float4 g = ((const float4*)gamma)[c4];
    float4 b = ((const float4*)beta)[c4];
    ushort4 hu = ((const ushort4*)hb)[i];
    float4 hv = make_float4(bf2f(hu.x), bf2f(hu.y), bf2f(hu.z), bf2f(hu.w));
    float4 xv = ((const float4*)xin)[i];
    float4 v = make_float4(fmaxf(g.x * (hv.x - mu.x) * inv.x + b.x, 0.f),
                           fmaxf(g.y * (hv.y - mu.y) * inv.y + b.y, 0.f),
                           fmaxf(g.z * (hv.z - mu.z) * inv.z + b.z, 0.f),
                           fmaxf(g.w * (hv.w - mu.w) * inv.w + b.w, 0.f));
    float4 o = make_float4(xv.x + v.x, xv.y + v.y, xv.z + v.z, xv.w + v.w);
    ((float4*)x)[i] = o;
    if (xbout) {
        ushort4 ob;
        ob.x = f2bf(o.x); ob.y = f2bf(o.y); ob.z = f2bf(o.z); ob.w = f2bf(o.w);
        xbout[i] = ob;
    }
}

// ---------------- launcher ----------------

extern "C" void kernel_launch(void* const* d_in, const int* in_sizes, int n_in,
                              void* d_out, int out_size, void* d_ws, size_t ws_size,
                              hipStream_t stream) {
    const float* x_in = (const float*)d_in[0];
    const int* ei = (const int*)d_in[1];
    // d_in[2] = edge_attr (unused)
    const float* ew = (const float*)d_in[3];
    const float* W1 = (const float*)d_in[4];
    const float* b1 = (const float*)d_in[5];
    const float* W2 = (const float*)d_in[6];
    const float* b2 = (const float*)d_in[7];
    const float* eps = (const float*)d_in[8];
    const float* gamma = (const float*)d_in[9];
    const float* beta = (const float*)d_in[10];

    float* x = (float*)d_out;  // running node features (fp32)

    char* ws = (char*)d_ws;
    unsigned short* g = (unsigned short*)ws;               // GIN input bf16 (12.8 MB)
    unsigned short* t = (unsigned short*)(ws + 12800000);  // MLP mid bf16   (12.8 MB)
    unsigned short* hb = (unsigned short*)(ws + 25600000); // MLP out bf16   (12.8 MB)
    unsigned short* xb = (unsigned short*)(ws + 38400000); // x mirror bf16  (12.8 MB)
    float* stats = (float*)(ws + 51200000);                // 256 floats (sum | sumsq)
    int* rowptr = (int*)(ws + 51201024);                   // 50001 ints
    int* cursor = (int*)(ws + 51401056);                   // 50000 ints
    int* counts = (int*)(ws + 51601056);                   // 50000 ints; overlaid by Wt after scan
    unsigned short* Wtall = (unsigned short*)(ws + 51601056);  // 6*16384 bf16
    int2* srcw = (int2*)(ws + 51801056);                   // 800000 int2 (src, weight-bits)
    int* bsum = (int*)(ws + 58201056);                     // 196 ints
    int* bbase = (int*)(ws + 58202080);                    // 196 ints

    const int n4x = NN * D4;

    // ---- CSR build (graph static across layers) ----
    zero_int<<<(NN + 255) / 256, 256, 0, stream>>>(counts, NN);
    hist_kernel<<<(NE + 255) / 256, 256, 0, stream>>>(ei, counts);
    block_sums<<<SCAN_NB, 256, 0, stream>>>(counts, bsum);
    scan_bsums<<<1, 256, 0, stream>>>(bsum, bbase);
    rowptr_fill<<<SCAN_NB, 256, 0, stream>>>(counts, bbase, rowptr, cursor);
    fill_kernel<<<(NE + 255) / 256, 256, 0, stream>>>(ei, ew, cursor, srcw);

    // weights -> bf16 transposed (after scan: Wtall overlays counts)
    prep_wt<<<(6 * 16384 + 255) / 256, 256, 0, stream>>>(W1, W2, Wtall);

    // bf16 mirror of x for layer-0 gather
    x2b<<<(n4x + 255) / 256, 256, 0, stream>>>((const float4*)x_in, (ushort4*)xb);

    const int gemmGrid = (NN + 127) / 128;  // 391

    for (int i = 0; i < 3; i++) {
        const float* b1i = b1 + i * DD;
        const float* b2i = b2 + i * DD;
        const unsigned short* Wt1 = Wtall + i * 16384;
        const unsigned short* Wt2 = Wtall + (3 + i) * 16384;
        const float* xsrc = (i == 0) ? x_in : x;

        // g = bf16((1+eps)*xb + sum w*xb[src]); zeroes stats
        gather_kernel<<<(NN + 7) / 8, 256, 0, stream>>>(xb, srcw, rowptr, eps + i, g, stats);

        // t = bf16(relu(g @ W1 + b1))
        mfma_gemm<0><<<gemmGrid, 256, 0, stream>>>(g, Wt1, b1i, t, nullptr);

        // hb = bf16(t @ W2 + b2), + BN stats (fp32)
        mfma_gemm<1><<<gemmGrid, 256, 0, stream>>>(t, Wt2, b2i, hb, stats);

        // x = xsrc + relu(bn(hb)); xb = bf16(x) for next gather (skip on last layer)
        bn_apply<<<(n4x + 255) / 256, 256, 0, stream>>>(hb, stats, gamma + i * DD,
                                                        beta + i * DD, xsrc, x,
                                                        (i < 2) ? (ushort4*)xb : nullptr);
    }
}